// Round 6
// baseline (403.703 us; speedup 1.0000x reference)
//
#include <hip/hip_runtime.h>
#include <stdint.h>

#define NB 4
#define SEQ 16384
#define CH 512
#define NH 16
#define HD 32
#define QKVC 1536
#define MROWS (NB * SEQ) /* 65536 */

typedef unsigned short u16;
typedef __attribute__((ext_vector_type(8))) short bf16x8;
typedef __attribute__((ext_vector_type(4))) float f32x4;

__device__ __forceinline__ float bf2f(u16 u) {
  union { unsigned int i; float f; } c; c.i = ((unsigned int)u) << 16; return c.f;
}
__device__ __forceinline__ u16 f2bf(float f) {
  union { float f; unsigned int i; } c; c.f = f;
  return (u16)((c.i + 0x7fffu + ((c.i >> 16) & 1u)) >> 16);
}

__device__ __forceinline__ void async16(const u16* g, u16* l) {
  __builtin_amdgcn_global_load_lds((const __attribute__((address_space(1))) void*)g,
                                   (__attribute__((address_space(3))) void*)l,
                                   16, 0, 0);
}

// ---------------------------------------------------------------------------
// Kernel 0: cast x / qkv_weight / proj_weight f32 -> bf16, zero vk accumulator
// ---------------------------------------------------------------------------
__global__ void prep_kernel(const float* __restrict__ x,
                            const float* __restrict__ qw,
                            const float* __restrict__ pw,
                            u16* __restrict__ xb,
                            u16* __restrict__ qwb,
                            u16* __restrict__ pwb,
                            float* __restrict__ vk) {
  int gid = blockIdx.x * blockDim.x + threadIdx.x;
  int stride = gridDim.x * blockDim.x;

  const float4* x4 = (const float4*)x;
  ushort4* xb4 = (ushort4*)xb;
  for (int i = gid; i < (MROWS * CH / 4); i += stride) {
    float4 v = x4[i];
    ushort4 o; o.x = f2bf(v.x); o.y = f2bf(v.y); o.z = f2bf(v.z); o.w = f2bf(v.w);
    xb4[i] = o;
  }
  const float4* q4 = (const float4*)qw;
  ushort4* qwb4 = (ushort4*)qwb;
  for (int i = gid; i < (QKVC * CH / 4); i += stride) {
    float4 v = q4[i];
    ushort4 o; o.x = f2bf(v.x); o.y = f2bf(v.y); o.z = f2bf(v.z); o.w = f2bf(v.w);
    qwb4[i] = o;
  }
  const float4* p4 = (const float4*)pw;
  ushort4* pwb4 = (ushort4*)pwb;
  for (int i = gid; i < (CH * CH / 4); i += stride) {
    float4 v = p4[i];
    ushort4 o; o.x = f2bf(v.x); o.y = f2bf(v.y); o.z = f2bf(v.z); o.w = f2bf(v.w);
    pwb4[i] = o;
  }
  float4 z; z.x = 0.f; z.y = 0.f; z.z = 0.f; z.w = 0.f;
  float4* vk4 = (float4*)vk;
  for (int i = gid; i < (NB * NH * 33 * 32 / 4); i += stride) vk4[i] = z;
}

// ---------------------------------------------------------------------------
// Persistent 8-phase 256x256 bf16 GEMM with counted-lgkm balanced phases.
// Per k-tile: ph0 issues 16 frag reads (gate lgkm(8), 8 MFMA), ph1/ph2 issue
// 4 trailing reads each behind their WAR producers (16 MFMA each), ph3 does
// 24 MFMA overlapping the vmcnt(4) staging gate. Restage-safety: every
// half-tile is restaged only after an all-waves barrier that follows the
// completion (counted lgkm) of every read of that half.
// ---------------------------------------------------------------------------
template <int N_DIM, bool RELU_QK, bool FINAL>
__global__ __launch_bounds__(512, 2) void gemm8p_kernel(
    const u16* __restrict__ A, const u16* __restrict__ Bm,
    void* __restrict__ Out, const float* __restrict__ bias) {
  constexpr int NT = N_DIM / 256;
  constexpr int NKT = NT * 8;
  __shared__ __align__(16) u16 lds[65536];  // 128 KiB

  const int tid = threadIdx.x;
  const int lane = tid & 63;
  const int w = tid >> 6;   // 0..7
  const int wr = w >> 2;    // 0..1  (M half)
  const int wc = w & 3;     // 0..3  (N quarter)
  const int fr = lane & 15;
  const int g = lane >> 4;
  const int xr = (fr & 7) << 3;  // read-side XOR (u16 units)

  // XCD-bijective block swizzle over 256 blocks
  int bid = blockIdx.x;
  bid = (bid & 7) * 32 + (bid >> 3);
  const long row0 = (long)bid * 256;

  const int trow = tid >> 3;                                        // 0..63
  const int tcol = ((tid & 7) * 8) ^ (((tid >> 3) & 7) << 3);       // u16 units

#define STAGE_A(ktf_, h_)                                                     \
  do {                                                                        \
    if ((ktf_) < NKT) {                                                       \
      u16* lb_ = &lds[(((ktf_) & 1) * 2 + (h_)) * 8192 + w * 512];            \
      const u16* ga_ = A + (size_t)(row0 + (h_) * 128 + trow) * 512 +         \
                       ((ktf_) & 7) * 64 + tcol;                              \
      async16(ga_, lb_);                                                      \
      async16(ga_ + 64 * 512, lb_ + 4096);                                    \
    }                                                                         \
  } while (0)

#define STAGE_B(ktf_, h_)                                                     \
  do {                                                                        \
    if ((ktf_) < NKT) {                                                       \
      u16* lb_ = &lds[32768 + (((ktf_) & 1) * 2 + (h_)) * 8192 + w * 512];    \
      const u16* gb_ = Bm + (size_t)(((ktf_) >> 3) * 256 + (h_) * 128 +       \
                                     trow) * 512 + ((ktf_) & 7) * 64 + tcol;  \
      async16(gb_, lb_);                                                      \
      async16(gb_ + 64 * 512, lb_ + 4096);                                    \
    }                                                                         \
  } while (0)

  f32x4 acc[8][4];
#pragma unroll
  for (int m = 0; m < 8; m++)
#pragma unroll
    for (int n = 0; n < 4; n++) {
      f32x4 z = {0.f, 0.f, 0.f, 0.f};
      acc[m][n] = z;
    }

  // prologue: ktf0 full + ktf1 lo-halves; gate ktf0.
  STAGE_B(0, 0); STAGE_A(0, 0); STAGE_B(0, 1); STAGE_A(0, 1);
  STAGE_B(1, 0); STAGE_A(1, 0);
  asm volatile("s_waitcnt vmcnt(4)" ::: "memory");
  __builtin_amdgcn_s_barrier();

#pragma unroll 2
  for (int ktf = 0; ktf < NKT; ++ktf) {
    const int abase = ((ktf & 1) * 2 + wr) * 8192;
    const int bbase = 32768 + ((ktf & 1) * 2 + (wc >> 1)) * 8192 + (wc & 1) * 4096;

#define RDA(m_, kk_) (*(const bf16x8*)&lds[abase + ((m_) * 16 + fr) * 64 + (((kk_) * 32 + g * 8) ^ xr)])
#define RDB(n_, kk_) (*(const bf16x8*)&lds[bbase + ((n_) * 16 + fr) * 64 + (((kk_) * 32 + g * 8) ^ xr)])

    bf16x8 rA[2][2], rB[2][2], b[4][2];

    // ---- ph0: issue a01(4) b01(4) a23(4) b23(4); stage B hi(kt+1); 8 MFMA
    rA[0][0] = RDA(0, 0); rA[0][1] = RDA(0, 1);
    rA[1][0] = RDA(1, 0); rA[1][1] = RDA(1, 1);
    b[0][0] = RDB(0, 0);  b[0][1] = RDB(0, 1);
    b[1][0] = RDB(1, 0);  b[1][1] = RDB(1, 1);
    rB[0][0] = RDA(2, 0); rB[0][1] = RDA(2, 1);
    rB[1][0] = RDA(3, 0); rB[1][1] = RDA(3, 1);
    b[2][0] = RDB(2, 0);  b[2][1] = RDB(2, 1);
    b[3][0] = RDB(3, 0);  b[3][1] = RDB(3, 1);
    STAGE_B(ktf + 1, 1);
    asm volatile("" ::: "memory");
    __builtin_amdgcn_s_barrier();
    asm volatile("s_waitcnt lgkmcnt(8)" ::: "memory");
    __builtin_amdgcn_s_setprio(1);
#pragma unroll
    for (int mm = 0; mm < 2; ++mm)
#pragma unroll
      for (int n = 0; n < 2; ++n)
#pragma unroll
        for (int kk = 0; kk < 2; ++kk)
          acc[mm][n] = __builtin_amdgcn_mfma_f32_16x16x32_bf16(rA[mm][kk], b[n][kk], acc[mm][n], 0, 0, 0);
    __builtin_amdgcn_s_setprio(0);
    asm volatile("" ::: "memory");
    __builtin_amdgcn_s_barrier();

    // ---- ph1: stage A hi(kt+1); 16 MFMA (m01xn23, m23xn01); issue a45->rA
    STAGE_A(ktf + 1, 1);
    asm volatile("" ::: "memory");
    __builtin_amdgcn_s_barrier();
    asm volatile("s_waitcnt lgkmcnt(0)" ::: "memory");
    __builtin_amdgcn_s_setprio(1);
#pragma unroll
    for (int mm = 0; mm < 2; ++mm)
#pragma unroll
      for (int n = 0; n < 2; ++n)
#pragma unroll
        for (int kk = 0; kk < 2; ++kk) {
          acc[mm][2 + n] = __builtin_amdgcn_mfma_f32_16x16x32_bf16(rA[mm][kk], b[2 + n][kk], acc[mm][2 + n], 0, 0, 0);
          acc[2 + mm][n] = __builtin_amdgcn_mfma_f32_16x16x32_bf16(rB[mm][kk], b[n][kk], acc[2 + mm][n], 0, 0, 0);
        }
    __builtin_amdgcn_s_setprio(0);
    rA[0][0] = RDA(4, 0); rA[0][1] = RDA(4, 1);   // WAR: after m01's last use
    rA[1][0] = RDA(5, 0); rA[1][1] = RDA(5, 1);
    asm volatile("" ::: "memory");
    __builtin_amdgcn_s_barrier();

    // ---- ph2: stage B lo(kt+2); 16 MFMA (m23xn23, m45xn01); issue a67->rB
    STAGE_B(ktf + 2, 0);
    asm volatile("" ::: "memory");
    __builtin_amdgcn_s_barrier();
    asm volatile("s_waitcnt lgkmcnt(0)" ::: "memory");
    __builtin_amdgcn_s_setprio(1);
#pragma unroll
    for (int mm = 0; mm < 2; ++mm)
#pragma unroll
      for (int n = 0; n < 2; ++n)
#pragma unroll
        for (int kk = 0; kk < 2; ++kk) {
          acc[2 + mm][2 + n] = __builtin_amdgcn_mfma_f32_16x16x32_bf16(rB[mm][kk], b[2 + n][kk], acc[2 + mm][2 + n], 0, 0, 0);
          acc[4 + mm][n] = __builtin_amdgcn_mfma_f32_16x16x32_bf16(rA[mm][kk], b[n][kk], acc[4 + mm][n], 0, 0, 0);
        }
    __builtin_amdgcn_s_setprio(0);
    rB[0][0] = RDA(6, 0); rB[0][1] = RDA(6, 1);   // WAR: after m23's last use
    rB[1][0] = RDA(7, 0); rB[1][1] = RDA(7, 1);
    asm volatile("" ::: "memory");
    __builtin_amdgcn_s_barrier();

    // ---- ph3: all reads complete -> barrier -> safe A lo(kt+2) restage;
    //          counted vmcnt gate; 24 MFMA (m45xn23, m67xn01, m67xn23)
    asm volatile("s_waitcnt lgkmcnt(0)" ::: "memory");
    __builtin_amdgcn_s_barrier();
    STAGE_A(ktf + 2, 0);
    if (ktf >= NKT - 2) {
      asm volatile("s_waitcnt vmcnt(0)" ::: "memory");
    } else {
      asm volatile("s_waitcnt vmcnt(4)" ::: "memory");
    }
    __builtin_amdgcn_s_setprio(1);
#pragma unroll
    for (int mm = 0; mm < 2; ++mm)
#pragma unroll
      for (int n = 0; n < 2; ++n)
#pragma unroll
        for (int kk = 0; kk < 2; ++kk) {
          acc[4 + mm][2 + n] = __builtin_amdgcn_mfma_f32_16x16x32_bf16(rA[mm][kk], b[2 + n][kk], acc[4 + mm][2 + n], 0, 0, 0);
          acc[6 + mm][n] = __builtin_amdgcn_mfma_f32_16x16x32_bf16(rB[mm][kk], b[n][kk], acc[6 + mm][n], 0, 0, 0);
          acc[6 + mm][2 + n] = __builtin_amdgcn_mfma_f32_16x16x32_bf16(rB[mm][kk], b[2 + n][kk], acc[6 + mm][2 + n], 0, 0, 0);
        }
    __builtin_amdgcn_s_setprio(0);
    asm volatile("" ::: "memory");
    __builtin_amdgcn_s_barrier();

    // ---- tile boundary: direct-store epilogue, reset acc; stores overlap
    // the next tile's first k-tile (drained by its ph3 vmcnt gate).
    if ((ktf & 7) == 7) {
      const long col0 = (long)(ktf >> 3) * 256;
      const long rbase = row0 + wr * 128;
      const long cbase = col0 + wc * 64;
#pragma unroll
      for (int m = 0; m < 8; ++m)
#pragma unroll
        for (int n = 0; n < 4; ++n)
#pragma unroll
          for (int j = 0; j < 4; ++j) {
            long gr = rbase + m * 16 + g * 4 + j;
            long gc = cbase + n * 16 + fr;
            float v = acc[m][n][j];
            if constexpr (FINAL) {
              ((float*)Out)[gr * N_DIM + gc] = v + bias[gc];
            } else {
              if (RELU_QK && gc < 1024) v = fmaxf(v, 0.f);
              ((u16*)Out)[gr * N_DIM + gc] = f2bf(v);
            }
          }
#pragma unroll
      for (int m = 0; m < 8; ++m)
#pragma unroll
        for (int n = 0; n < 4; ++n) {
          f32x4 z = {0.f, 0.f, 0.f, 0.f};
          acc[m][n] = z;
        }
    }
#undef RDA
#undef RDB
  }
#undef STAGE_A
#undef STAGE_B
}

// ---------------------------------------------------------------------------
// Kernel 2 (MFMA): vk[b,h,c,d] = sum_n v[n,h,c]*k[n,h,d], row 32 = sum_n k.
// ---------------------------------------------------------------------------
__global__ __launch_bounds__(256) void vk_kernel(const u16* __restrict__ qkv,
                                                 float* __restrict__ vk) {
  __shared__ u16 tile[4][64 * 64];   // 32 KB
  __shared__ float red[1056];        // 4.2 KB block accumulator

  const int tid = threadIdx.x;
  const int lane = tid & 63;
  const int w = tid >> 6;

  for (int i = tid; i < 1056; i += 256) red[i] = 0.f;
  __syncthreads();

  const int bh = blockIdx.x >> 4;
  const int split = blockIdx.x & 15;
  const int b = bh >> 4, h = bh & 15;

  const int s = lane & 7;   // column segment: 0-3 -> k, 4-7 -> v
  const int rl = lane >> 3; // row within 8-row staging group
  const size_t gbase = (size_t)b * SEQ * QKVC + 512 + (size_t)(s >> 2) * 512 +
                       h * 32 + (s & 3) * 8;

  f32x4 acc[2][2];
  f32x4 accs[2];
#pragma unroll
  for (int tc = 0; tc < 2; tc++) {
    f32x4 z = {0.f, 0.f, 0.f, 0.f};
    accs[tc] = z;
#pragma unroll
    for (int td = 0; td < 2; td++) acc[tc][td] = z;
  }
  bf16x8 ones;
#pragma unroll
  for (int j = 0; j < 8; j++) ones[j] = (short)0x3F80;  // bf16 1.0

  const int m = lane & 15;
  const int g = lane >> 4;
  u16* tw = tile[w];
  const int n0w = split * 1024 + w * 256;

  for (int t = 0; t < 4; ++t) {
    const int nt = n0w + t * 64;
#pragma unroll
    for (int p = 0; p < 8; ++p)
      async16(qkv + gbase + (size_t)(nt + p * 8 + rl) * QKVC, &tw[p * 512]);
    asm volatile("s_waitcnt vmcnt(0)" ::: "memory");
#pragma unroll
    for (int kk = 0; kk < 2; ++kk) {
      bf16x8 av[2], bk[2];
#pragma unroll
      for (int tc = 0; tc < 2; tc++)
#pragma unroll
        for (int j = 0; j < 8; j++)
          av[tc][j] = (short)tw[(kk * 32 + g * 8 + j) * 64 + 32 + tc * 16 + m];
#pragma unroll
      for (int td = 0; td < 2; td++)
#pragma unroll
        for (int j = 0; j < 8; j++)
          bk[td][j] = (short)tw[(kk * 32 + g * 8 + j) * 64 + td * 16 + m];
#pragma unroll
      for (int tc = 0; tc < 2; tc++)
#pragma unroll
        for (int td = 0; td < 2; td++)
          acc[tc][td] = __builtin_amdgcn_mfma_f32_16x16x32_bf16(av[tc], bk[td], acc[tc][td], 0, 0, 0);
#pragma unroll
      for (int td = 0; td < 2; td++)
        accs[td] = __builtin_amdgcn_mfma_f32_16x16x32_bf16(ones, bk[td], accs[td], 0, 0, 0);
    }
  }

#pragma unroll
  for (int tc = 0; tc < 2; tc++)
#pragma unroll
    for (int td = 0; td < 2; td++)
#pragma unroll
      for (int j = 0; j < 4; j++)
        atomicAdd(&red[(tc * 16 + g * 4 + j) * 32 + td * 16 + m], acc[tc][td][j]);
  if (lane < 16) {
#pragma unroll
    for (int td = 0; td < 2; td++)
      atomicAdd(&red[1024 + td * 16 + lane], accs[td][0]);
  }
  __syncthreads();
  float* dst = vk + (size_t)bh * 1056;
  for (int i = tid; i < 1056; i += 256) atomicAdd(&dst[i], red[i]);
}

// ---------------------------------------------------------------------------
// Kernel 3 (MFMA): vk_q + divide -> proj_input (bf16).
// ---------------------------------------------------------------------------
__global__ __launch_bounds__(256) void vkq_kernel(const u16* __restrict__ qkv,
                                                  const float* __restrict__ vk,
                                                  u16* __restrict__ pi) {
  __shared__ u16 bhi[NH * 33 * 34];  // 35.9 KB
  __shared__ u16 blo[NH * 33 * 34];  // 35.9 KB

  const int tid = threadIdx.x;
  const int b = blockIdx.x >> 8;           // 256 blocks per batch
  const int n0 = (blockIdx.x & 255) * 64;

  const float* vg = vk + (size_t)b * NH * 1056;
#pragma unroll 1
  for (int h = 0; h < NH; ++h)
    for (int r = tid; r < 1056; r += 256) {
      int c = r >> 5, d = r & 31;
      float v = vg[h * 1056 + r];
      u16 hv = f2bf(v);
      float lo = v - bf2f(hv);
      int dst = h * (33 * 34) + c * 34 + d;
      bhi[dst] = hv;
      blo[dst] = f2bf(lo);
    }
  __syncthreads();

  const int lane = tid & 63;
  const int w = tid >> 6;
  const int fr = lane & 15;
  const int g = lane >> 4;

  const u16* qbase = qkv + ((size_t)b * SEQ + n0 + w * 16 + fr) * QKVC;
  u16* pbase = pi + ((size_t)b * SEQ + n0 + w * 16 + g * 4) * CH;

  for (int h = 0; h < NH; ++h) {
    bf16x8 a = *(const bf16x8*)(qbase + h * 32 + g * 8);
    const int tb = h * (33 * 34);
    bf16x8 h0 = *(const bf16x8*)&bhi[tb + fr * 34 + g * 8];
    bf16x8 l0 = *(const bf16x8*)&blo[tb + fr * 34 + g * 8];
    bf16x8 h1 = *(const bf16x8*)&bhi[tb + (16 + fr) * 34 + g * 8];
    bf16x8 l1 = *(const bf16x8*)&blo[tb + (16 + fr) * 34 + g * 8];
    bf16x8 h2, l2;
#pragma unroll
    for (int j = 0; j < 8; ++j) { h2[j] = 0; l2[j] = 0; }
    if (fr == 0) {
      h2 = *(const bf16x8*)&bhi[tb + 32 * 34 + g * 8];
      l2 = *(const bf16x8*)&blo[tb + 32 * 34 + g * 8];
    }
    f32x4 z = {0.f, 0.f, 0.f, 0.f};
    f32x4 c0 = __builtin_amdgcn_mfma_f32_16x16x32_bf16(a, l0, z, 0, 0, 0);
    c0 = __builtin_amdgcn_mfma_f32_16x16x32_bf16(a, h0, c0, 0, 0, 0);
    f32x4 c1 = __builtin_amdgcn_mfma_f32_16x16x32_bf16(a, l1, z, 0, 0, 0);
    c1 = __builtin_amdgcn_mfma_f32_16x16x32_bf16(a, h1, c1, 0, 0, 0);
    f32x4 c2 = __builtin_amdgcn_mfma_f32_16x16x32_bf16(a, l2, z, 0, 0, 0);
    c2 = __builtin_amdgcn_mfma_f32_16x16x32_bf16(a, h2, c2, 0, 0, 0);
#pragma unroll
    for (int j = 0; j < 4; ++j) {
      float den = __shfl(c2[j], lane & 48);  // fr=0 lane of same g
      float r = 1.0f / (den + 1e-15f);
      pbase[(size_t)j * CH + h * 32 + fr] = f2bf(c0[j] * r);
      pbase[(size_t)j * CH + h * 32 + 16 + fr] = f2bf(c1[j] * r);
    }
  }
}

// ---------------------------------------------------------------------------
extern "C" void kernel_launch(void* const* d_in, const int* in_sizes, int n_in,
                              void* d_out, int out_size, void* d_ws, size_t ws_size,
                              hipStream_t stream) {
  const float* x = (const float*)d_in[0];
  const float* qw = (const float*)d_in[1];
  const float* pw = (const float*)d_in[2];
  const float* bias = (const float*)d_in[3];

  char* ws = (char*)d_ws;
  u16* qkv = (u16*)(ws);                      // 65536*1536*2 = 201326592 B
  u16* xb = (u16*)(ws + 201326592);           // 65536*512*2  =  67108864 B
  u16* qwb = (u16*)(ws + 268435456);          // 1536*512*2   =   1572864 B
  u16* pwb = (u16*)(ws + 270008320);          // 512*512*2    =    524288 B
  float* vk = (float*)(ws + 270532608);       // 64*1056*4    =    270336 B
  u16* pi = xb;  // alias: x_bf16 dead after QKV GEMM; reuse for proj_input

  prep_kernel<<<2048, 256, 0, stream>>>(x, qw, pw, xb, qwb, pwb, vk);
  gemm8p_kernel<QKVC, true, false><<<256, 512, 0, stream>>>(xb, qwb, qkv, nullptr);
  vk_kernel<<<NB * NH * 16, 256, 0, stream>>>(qkv, vk);
  vkq_kernel<<<NB * (SEQ / 64), 256, 0, stream>>>(qkv, vk, pi);
  gemm8p_kernel<CH, false, true><<<256, 512, 0, stream>>>(pi, pwb, d_out, bias);
}

// Round 7
// 319.555 us; speedup vs baseline: 1.2633x; 1.2633x over previous
//
#include <hip/hip_runtime.h>
#include <stdint.h>

#define NB 4
#define SEQ 16384
#define CH 512
#define NH 16
#define HD 32
#define QKVC 1536
#define MROWS (NB * SEQ) /* 65536 */

typedef unsigned short u16;
typedef __attribute__((ext_vector_type(8))) short bf16x8;
typedef __attribute__((ext_vector_type(4))) float f32x4;

__device__ __forceinline__ float bf2f(u16 u) {
  union { unsigned int i; float f; } c; c.i = ((unsigned int)u) << 16; return c.f;
}
__device__ __forceinline__ u16 f2bf(float f) {
  union { float f; unsigned int i; } c; c.f = f;
  return (u16)((c.i + 0x7fffu + ((c.i >> 16) & 1u)) >> 16);
}

__device__ __forceinline__ void async16(const u16* g, u16* l) {
  __builtin_amdgcn_global_load_lds((const __attribute__((address_space(1))) void*)g,
                                   (__attribute__((address_space(3))) void*)l,
                                   16, 0, 0);
}

// ---------------------------------------------------------------------------
// Kernel 0: cast x / qkv_weight / proj_weight f32 -> bf16, zero vk accumulator
// ---------------------------------------------------------------------------
__global__ void prep_kernel(const float* __restrict__ x,
                            const float* __restrict__ qw,
                            const float* __restrict__ pw,
                            u16* __restrict__ xb,
                            u16* __restrict__ qwb,
                            u16* __restrict__ pwb,
                            float* __restrict__ vk) {
  int gid = blockIdx.x * blockDim.x + threadIdx.x;
  int stride = gridDim.x * blockDim.x;

  const float4* x4 = (const float4*)x;
  ushort4* xb4 = (ushort4*)xb;
  for (int i = gid; i < (MROWS * CH / 4); i += stride) {
    float4 v = x4[i];
    ushort4 o; o.x = f2bf(v.x); o.y = f2bf(v.y); o.z = f2bf(v.z); o.w = f2bf(v.w);
    xb4[i] = o;
  }
  const float4* q4 = (const float4*)qw;
  ushort4* qwb4 = (ushort4*)qwb;
  for (int i = gid; i < (QKVC * CH / 4); i += stride) {
    float4 v = q4[i];
    ushort4 o; o.x = f2bf(v.x); o.y = f2bf(v.y); o.z = f2bf(v.z); o.w = f2bf(v.w);
    qwb4[i] = o;
  }
  const float4* p4 = (const float4*)pw;
  ushort4* pwb4 = (ushort4*)pwb;
  for (int i = gid; i < (CH * CH / 4); i += stride) {
    float4 v = p4[i];
    ushort4 o; o.x = f2bf(v.x); o.y = f2bf(v.y); o.z = f2bf(v.z); o.w = f2bf(v.w);
    pwb4[i] = o;
  }
  float4 z; z.x = 0.f; z.y = 0.f; z.z = 0.f; z.w = 0.f;
  float4* vk4 = (float4*)vk;
  for (int i = gid; i < (NB * NH * 33 * 32 / 4); i += stride) vk4[i] = z;
}

// ---------------------------------------------------------------------------
// 8-phase 256x256 bf16 GEMM (r3 structure, best measured). Grid-tiled 2D,
// BK=64, 8 waves (2Mx4N), per-wave 128x64. XOR-swizzled LDS both sides.
// Counted vmcnt(4) per k-tile; direct-store epilogue.
// SPLIT3: output cols [0,512)->OutQ relu, [512,1024)->OutK relu,
// [1024,1536)->OutV, each ldc=512 bf16. FINAL: f32 + bias, ldc=N_DIM.
// ---------------------------------------------------------------------------
template <int N_DIM, bool SPLIT3, bool FINAL>
__global__ __launch_bounds__(512, 2) void gemm8p_kernel(
    const u16* __restrict__ A, const u16* __restrict__ Bm,
    void* __restrict__ Out, u16* __restrict__ OutK, u16* __restrict__ OutV,
    const float* __restrict__ bias) {
  __shared__ __align__(16) u16 lds[65536];  // 128 KiB

  const int tid = threadIdx.x;
  const int lane = tid & 63;
  const int w = tid >> 6;   // 0..7
  const int wr = w >> 2;    // 0..1  (M half)
  const int wc = w & 3;     // 0..3  (N quarter)
  const int fr = lane & 15;
  const int g = lane >> 4;
  const int xr = (fr & 7) << 3;  // read-side XOR (u16 units)

  // XCD-bijective block swizzle (nwg % 8 == 0 for both shapes)
  const int gridX = N_DIM / 256;
  const int nwg = gridX * (MROWS / 256);
  int bid = blockIdx.y * gridX + blockIdx.x;
  bid = (bid & 7) * (nwg >> 3) + (bid >> 3);
  const long row0 = (long)(bid / gridX) * 256;
  const long col0 = (long)(bid % gridX) * 256;

  // staging: source element pre-swizzled so swizzled read returns linear data.
  const int trow = tid >> 3;                                        // 0..63
  const int tcol = ((tid & 7) * 8) ^ (((tid >> 3) & 7) << 3);       // u16 units

#define STAGE_A(kt_, h_)                                                      \
  do {                                                                        \
    u16* lb_ = &lds[(((kt_) & 1) * 2 + (h_)) * 8192 + w * 512];               \
    const u16* ga_ = A + (size_t)(row0 + (h_) * 128 + trow) * 512 +           \
                     (kt_) * 64 + tcol;                                       \
    async16(ga_, lb_);                                                        \
    async16(ga_ + 64 * 512, lb_ + 4096);                                      \
  } while (0)

#define STAGE_B(kt_, h_)                                                      \
  do {                                                                        \
    u16* lb_ = &lds[32768 + (((kt_) & 1) * 2 + (h_)) * 8192 + w * 512];       \
    const u16* gb_ = Bm + (size_t)(col0 + (h_) * 128 + trow) * 512 +          \
                     (kt_) * 64 + tcol;                                       \
    async16(gb_, lb_);                                                        \
    async16(gb_ + 64 * 512, lb_ + 4096);                                      \
  } while (0)

  f32x4 acc[8][4];
#pragma unroll
  for (int m = 0; m < 8; m++)
#pragma unroll
    for (int n = 0; n < 4; n++) {
      f32x4 z = {0.f, 0.f, 0.f, 0.f};
      acc[m][n] = z;
    }
  bf16x8 a[4][2], b[4][2];

  // prologue: stage B0(0),A0(0),B1(0),A1(0),B0(1),A0(1); gate first 4.
  STAGE_B(0, 0); STAGE_A(0, 0); STAGE_B(0, 1); STAGE_A(0, 1);
  STAGE_B(1, 0); STAGE_A(1, 0);
  asm volatile("s_waitcnt vmcnt(4)" ::: "memory");
  __builtin_amdgcn_s_barrier();

#pragma unroll
  for (int kt = 0; kt < 8; ++kt) {
    const int abase = ((kt & 1) * 2 + wr) * 8192;
    const int bbase = 32768 + ((kt & 1) * 2 + (wc >> 1)) * 8192 + (wc & 1) * 4096;

    // ---- phase 0: read A m0-3 + B n0-1; stage B hi(kt+1); MFMA q(m0-3,n0-1)
#pragma unroll
    for (int m = 0; m < 4; ++m)
#pragma unroll
      for (int kk = 0; kk < 2; ++kk)
        a[m][kk] = *(const bf16x8*)&lds[abase + (m * 16 + fr) * 64 + ((kk * 32 + g * 8) ^ xr)];
#pragma unroll
    for (int n = 0; n < 2; ++n)
#pragma unroll
      for (int kk = 0; kk < 2; ++kk)
        b[n][kk] = *(const bf16x8*)&lds[bbase + (n * 16 + fr) * 64 + ((kk * 32 + g * 8) ^ xr)];
    if (kt < 7) STAGE_B(kt + 1, 1);
    __builtin_amdgcn_s_barrier();
    asm volatile("s_waitcnt lgkmcnt(0)" ::: "memory");
    __builtin_amdgcn_s_setprio(1);
#pragma unroll
    for (int m = 0; m < 4; ++m)
#pragma unroll
      for (int n = 0; n < 2; ++n)
#pragma unroll
        for (int kk = 0; kk < 2; ++kk)
          acc[m][n] = __builtin_amdgcn_mfma_f32_16x16x32_bf16(a[m][kk], b[n][kk], acc[m][n], 0, 0, 0);
    __builtin_amdgcn_s_setprio(0);
    __builtin_amdgcn_s_barrier();

    // ---- phase 1: read B n2-3; stage A hi(kt+1); MFMA q(m0-3,n2-3)
#pragma unroll
    for (int n = 0; n < 2; ++n)
#pragma unroll
      for (int kk = 0; kk < 2; ++kk)
        b[2 + n][kk] = *(const bf16x8*)&lds[bbase + ((n + 2) * 16 + fr) * 64 + ((kk * 32 + g * 8) ^ xr)];
    if (kt < 7) STAGE_A(kt + 1, 1);
    __builtin_amdgcn_s_barrier();
    asm volatile("s_waitcnt lgkmcnt(0)" ::: "memory");
    __builtin_amdgcn_s_setprio(1);
#pragma unroll
    for (int m = 0; m < 4; ++m)
#pragma unroll
      for (int n = 0; n < 2; ++n)
#pragma unroll
        for (int kk = 0; kk < 2; ++kk)
          acc[m][2 + n] = __builtin_amdgcn_mfma_f32_16x16x32_bf16(a[m][kk], b[2 + n][kk], acc[m][2 + n], 0, 0, 0);
    __builtin_amdgcn_s_setprio(0);
    __builtin_amdgcn_s_barrier();

    // ---- phase 2: read A m4-7 (reuse regs); stage B lo(kt+2); MFMA q(m4-7,n2-3)
#pragma unroll
    for (int m = 0; m < 4; ++m)
#pragma unroll
      for (int kk = 0; kk < 2; ++kk)
        a[m][kk] = *(const bf16x8*)&lds[abase + ((m + 4) * 16 + fr) * 64 + ((kk * 32 + g * 8) ^ xr)];
    if (kt < 6) STAGE_B(kt + 2, 0);
    __builtin_amdgcn_s_barrier();
    asm volatile("s_waitcnt lgkmcnt(0)" ::: "memory");
    __builtin_amdgcn_s_setprio(1);
#pragma unroll
    for (int m = 0; m < 4; ++m)
#pragma unroll
      for (int n = 0; n < 2; ++n)
#pragma unroll
        for (int kk = 0; kk < 2; ++kk)
          acc[4 + m][2 + n] = __builtin_amdgcn_mfma_f32_16x16x32_bf16(a[m][kk], b[2 + n][kk], acc[4 + m][2 + n], 0, 0, 0);
    __builtin_amdgcn_s_setprio(0);
    __builtin_amdgcn_s_barrier();

    // ---- phase 3: stage A lo(kt+2); counted vmcnt gate; MFMA q(m4-7,n0-1)
    if (kt < 6) {
      STAGE_A(kt + 2, 0);
      asm volatile("s_waitcnt vmcnt(4)" ::: "memory");
    } else {
      asm volatile("s_waitcnt vmcnt(0)" ::: "memory");
    }
    __builtin_amdgcn_s_barrier();
    __builtin_amdgcn_s_setprio(1);
#pragma unroll
    for (int m = 0; m < 4; ++m)
#pragma unroll
      for (int n = 0; n < 2; ++n)
#pragma unroll
        for (int kk = 0; kk < 2; ++kk)
          acc[4 + m][n] = __builtin_amdgcn_mfma_f32_16x16x32_bf16(a[m][kk], b[n][kk], acc[4 + m][n], 0, 0, 0);
    __builtin_amdgcn_s_setprio(0);
    __builtin_amdgcn_s_barrier();
  }
#undef STAGE_A
#undef STAGE_B

  // epilogue: direct stores. rows row0+wr*128+m*16+g*4+j, cols col0+wc*64+n*16+fr
  const long rbase = row0 + wr * 128;
  if constexpr (SPLIT3) {
    const int bufi = (int)(col0 >> 9);  // 256-tile never straddles 512 boundary
    u16* ob = bufi == 0 ? (u16*)Out : (bufi == 1 ? OutK : OutV);
    const bool dorelu = bufi < 2;
    const long cbase = (col0 & 511) + wc * 64;
#pragma unroll
    for (int m = 0; m < 8; ++m)
#pragma unroll
      for (int n = 0; n < 4; ++n)
#pragma unroll
        for (int j = 0; j < 4; ++j) {
          long gr = rbase + m * 16 + g * 4 + j;
          long gc = cbase + n * 16 + fr;
          float v = acc[m][n][j];
          if (dorelu) v = fmaxf(v, 0.f);
          ob[gr * 512 + gc] = f2bf(v);
        }
  } else {
    const long cbase = col0 + wc * 64;
#pragma unroll
    for (int m = 0; m < 8; ++m)
#pragma unroll
      for (int n = 0; n < 4; ++n)
#pragma unroll
        for (int j = 0; j < 4; ++j) {
          long gr = rbase + m * 16 + g * 4 + j;
          long gc = cbase + n * 16 + fr;
          float v = acc[m][n][j];
          if constexpr (FINAL) {
            ((float*)Out)[gr * N_DIM + gc] = v + bias[gc];
          } else {
            ((u16*)Out)[gr * N_DIM + gc] = f2bf(v);
          }
        }
  }
}

// ---------------------------------------------------------------------------
// Kernel 2 (MFMA): vk[b,h,c,d] = sum_n v[n,h,c]*k[n,h,d], row 32 = sum_n k.
// k, v now in separate [MROWS,512] buffers (3x better line utilization).
// ---------------------------------------------------------------------------
__global__ __launch_bounds__(256) void vk_kernel(const u16* __restrict__ kb,
                                                 const u16* __restrict__ vb,
                                                 float* __restrict__ vk) {
  __shared__ u16 tile[4][64 * 64];   // 32 KB
  __shared__ float red[1056];        // 4.2 KB block accumulator

  const int tid = threadIdx.x;
  const int lane = tid & 63;
  const int w = tid >> 6;

  for (int i = tid; i < 1056; i += 256) red[i] = 0.f;
  __syncthreads();

  const int bh = blockIdx.x >> 4;
  const int split = blockIdx.x & 15;
  const int b = bh >> 4, h = bh & 15;

  const int s = lane & 7;   // column segment: 0-3 -> k, 4-7 -> v
  const int rl = lane >> 3; // row within 8-row staging group
  const u16* src = (s & 4) ? vb : kb;
  const size_t gbase = (size_t)b * SEQ * 512 + h * 32 + (s & 3) * 8;

  f32x4 acc[2][2];
  f32x4 accs[2];
#pragma unroll
  for (int tc = 0; tc < 2; tc++) {
    f32x4 z = {0.f, 0.f, 0.f, 0.f};
    accs[tc] = z;
#pragma unroll
    for (int td = 0; td < 2; td++) acc[tc][td] = z;
  }
  bf16x8 ones;
#pragma unroll
  for (int j = 0; j < 8; j++) ones[j] = (short)0x3F80;  // bf16 1.0

  const int m = lane & 15;
  const int g = lane >> 4;
  u16* tw = tile[w];
  const int n0w = split * 1024 + w * 256;

  for (int t = 0; t < 4; ++t) {
    const int nt = n0w + t * 64;
#pragma unroll
    for (int p = 0; p < 8; ++p)
      async16(src + gbase + (size_t)(nt + p * 8 + rl) * 512, &tw[p * 512]);
    asm volatile("s_waitcnt vmcnt(0)" ::: "memory");
#pragma unroll
    for (int kk = 0; kk < 2; ++kk) {
      bf16x8 av[2], bk[2];
#pragma unroll
      for (int tc = 0; tc < 2; tc++)
#pragma unroll
        for (int j = 0; j < 8; j++)
          av[tc][j] = (short)tw[(kk * 32 + g * 8 + j) * 64 + 32 + tc * 16 + m];
#pragma unroll
      for (int td = 0; td < 2; td++)
#pragma unroll
        for (int j = 0; j < 8; j++)
          bk[td][j] = (short)tw[(kk * 32 + g * 8 + j) * 64 + td * 16 + m];
#pragma unroll
      for (int tc = 0; tc < 2; tc++)
#pragma unroll
        for (int td = 0; td < 2; td++)
          acc[tc][td] = __builtin_amdgcn_mfma_f32_16x16x32_bf16(av[tc], bk[td], acc[tc][td], 0, 0, 0);
#pragma unroll
      for (int td = 0; td < 2; td++)
        accs[td] = __builtin_amdgcn_mfma_f32_16x16x32_bf16(ones, bk[td], accs[td], 0, 0, 0);
    }
  }

#pragma unroll
  for (int tc = 0; tc < 2; tc++)
#pragma unroll
    for (int td = 0; td < 2; td++)
#pragma unroll
      for (int j = 0; j < 4; j++)
        atomicAdd(&red[(tc * 16 + g * 4 + j) * 32 + td * 16 + m], acc[tc][td][j]);
  if (lane < 16) {
#pragma unroll
    for (int td = 0; td < 2; td++)
      atomicAdd(&red[1024 + td * 16 + lane], accs[td][0]);
  }
  __syncthreads();
  float* dst = vk + (size_t)bh * 1056;
  for (int i = tid; i < 1056; i += 256) atomicAdd(&dst[i], red[i]);
}

// ---------------------------------------------------------------------------
// Kernel 3: vk_q + divide -> proj_input (bf16). Thread owns one (n,h) pair.
// q now in its own [MROWS,512] buffer.
// ---------------------------------------------------------------------------
__global__ __launch_bounds__(256) void vkq_kernel(const u16* __restrict__ qb,
                                                  const float* __restrict__ vk,
                                                  u16* __restrict__ pi) {
  __shared__ float vkl[8 * 1056];  // 33.8 KB
  __shared__ u16 ob[32 * 256];     // 16 KB output bounce

  const int tid = threadIdx.x;
  const int chunk = blockIdx.x & 511;
  const int hh = (blockIdx.x >> 9) & 1;
  const int b = blockIdx.x >> 10;
  const int n0 = chunk * 32;

  const float* vg = vk + (size_t)(b * NH + hh * 8) * 1056;
  for (int i = tid; i < 8 * 1056; i += 256) vkl[i] = vg[i];
  __syncthreads();

  const int nl = tid & 31;
  const int hl = tid >> 5;
  const float* vkh = &vkl[hl * 1056];

  const u16* qp = qb + ((size_t)b * SEQ + n0 + nl) * 512 + (hh * 8 + hl) * 32;
  float qf[32];
#pragma unroll
  for (int s2 = 0; s2 < 4; ++s2) {
    bf16x8 qv = *(const bf16x8*)(qp + s2 * 8);
#pragma unroll
    for (int j = 0; j < 8; ++j) qf[s2 * 8 + j] = bf2f((u16)qv[j]);
  }

  float num[32];
#pragma unroll
  for (int c = 0; c < 32; ++c) {
    float a = 0.f;
#pragma unroll
    for (int d4 = 0; d4 < 8; ++d4) {
      f32x4 vv = *(const f32x4*)&vkh[c * 32 + d4 * 4];
      a = fmaf(qf[d4 * 4 + 0], vv[0], a);
      a = fmaf(qf[d4 * 4 + 1], vv[1], a);
      a = fmaf(qf[d4 * 4 + 2], vv[2], a);
      a = fmaf(qf[d4 * 4 + 3], vv[3], a);
    }
    num[c] = a;
  }
  float den = 0.f;
#pragma unroll
  for (int d4 = 0; d4 < 8; ++d4) {
    f32x4 vv = *(const f32x4*)&vkh[32 * 32 + d4 * 4];
    den = fmaf(qf[d4 * 4 + 0], vv[0], den);
    den = fmaf(qf[d4 * 4 + 1], vv[1], den);
    den = fmaf(qf[d4 * 4 + 2], vv[2], den);
    den = fmaf(qf[d4 * 4 + 3], vv[3], den);
  }
  const float r = 1.0f / (den + 1e-15f);
#pragma unroll
  for (int c = 0; c < 32; ++c) ob[nl * 256 + hl * 32 + c] = f2bf(num[c] * r);
  __syncthreads();

  u16* pg = pi + ((size_t)b * SEQ + n0) * CH + hh * 256;
  for (int i = tid; i < 1024; i += 256) {
    const int n = i >> 5;
    const int u = i & 31;
    *(bf16x8*)(pg + (size_t)n * CH + u * 8) = *(const bf16x8*)&ob[i * 8];
  }
}

// ---------------------------------------------------------------------------
extern "C" void kernel_launch(void* const* d_in, const int* in_sizes, int n_in,
                              void* d_out, int out_size, void* d_ws, size_t ws_size,
                              hipStream_t stream) {
  const float* x = (const float*)d_in[0];
  const float* qw = (const float*)d_in[1];
  const float* pw = (const float*)d_in[2];
  const float* bias = (const float*)d_in[3];

  char* ws = (char*)d_ws;
  u16* qb = (u16*)(ws);                       // 65536*512*2 = 67108864 B
  u16* kb = (u16*)(ws + 67108864);            // 67108864 B
  u16* vb = (u16*)(ws + 134217728);           // 67108864 B
  u16* xb = (u16*)(ws + 201326592);           // 67108864 B
  u16* qwb = (u16*)(ws + 268435456);          // 1536*512*2 = 1572864 B
  u16* pwb = (u16*)(ws + 270008320);          // 512*512*2  =  524288 B
  float* vk = (float*)(ws + 270532608);       // 64*1056*4  =  270336 B
  u16* pi = xb;  // alias: x_bf16 dead after QKV GEMM; reuse for proj_input

  prep_kernel<<<2048, 256, 0, stream>>>(x, qw, pw, xb, qwb, pwb, vk);
  gemm8p_kernel<QKVC, true, false>
      <<<dim3(QKVC / 256, MROWS / 256), 512, 0, stream>>>(xb, qwb, qb, kb, vb, nullptr);
  vk_kernel<<<NB * NH * 16, 256, 0, stream>>>(kb, vb, vk);
  vkq_kernel<<<NB * 2 * (SEQ / 32), 256, 0, stream>>>(qb, vk, pi);
  gemm8p_kernel<CH, false, true>
      <<<dim3(CH / 256, MROWS / 256), 512, 0, stream>>>(pi, pwb, d_out, nullptr, nullptr, bias);
}